// Round 9
// baseline (201.452 us; speedup 1.0000x reference)
//
#include <hip/hip_runtime.h>

#define E_ 1024
#define H_ 16
#define D_ 64
#define K_ 4
#define S_ 2048
#define B_ 2
#define BS_ 4096
#define BH_ 32
#define CT_ 2080

typedef __attribute__((ext_vector_type(8))) short short8;
typedef __attribute__((ext_vector_type(4))) float f32x4;
typedef __attribute__((ext_vector_type(4))) unsigned short u16x4;

__device__ __forceinline__ unsigned short f2bf(float f) {
  union { float f; unsigned u; } v; v.f = f;
  unsigned r = v.u + 0x7FFFu + ((v.u >> 16) & 1u);
  return (unsigned short)(r >> 16);
}
__device__ __forceinline__ float bf2f(unsigned short u) {
  union { unsigned u; float f; } v; v.u = ((unsigned)u) << 16; return v.f;
}

typedef __attribute__((address_space(1))) const void gvoid;
typedef __attribute__((address_space(3))) void lvoid;
__device__ __forceinline__ void gload_lds16(const void* g, void* l) {
  __builtin_amdgcn_global_load_lds((gvoid*)g, (lvoid*)l, 16, 0, 0);
}

// swizzled LDS read: 128B rows, 8 x 16B chunks, chunk ^= (row&7)
__device__ __forceinline__ short8 lds8(const unsigned short* base, int row, int chunk) {
  int off = row * 128 + (((chunk ^ (row & 7)) & 7) << 4);
  return *(const short8*)((const char*)base + off);
}

// 16-lane max reduce: xor1/xor2 via DPP quad_perm, xor4/8 via shfl (proven form)
__device__ __forceinline__ float redmax16(float v) {
  int iv = __float_as_int(v);
  v = fmaxf(v, __int_as_float(__builtin_amdgcn_update_dpp(iv, iv, 0xB1, 0xF, 0xF, true)));
  iv = __float_as_int(v);
  v = fmaxf(v, __int_as_float(__builtin_amdgcn_update_dpp(iv, iv, 0x4E, 0xF, 0xF, true)));
  v = fmaxf(v, __shfl_xor(v, 4, 16));
  v = fmaxf(v, __shfl_xor(v, 8, 16));
  return v;
}

// ---------------- fused prep: convert_x + transpose_w + rope cache + router ----------------
__global__ __launch_bounds__(256) void k_prep(const float* __restrict__ x,
    const float* __restrict__ Wq, const float* __restrict__ Wk, const float* __restrict__ Wv,
    const float* __restrict__ Wo, const float* __restrict__ Wr,
    unsigned short* __restrict__ xb, unsigned short* __restrict__ wt,
    float* __restrict__ cosc, float* __restrict__ sinc, float* __restrict__ logits) {
  __shared__ __align__(16) char smem[40960];
  int blk = blockIdx.x;
  int t = threadIdx.x;

  if (blk < 4096) {                     // ---- x -> bf16
    int i = blk * 256 + t;
    float4 v = ((const float4*)x)[i];
    u16x4 o; o.x = f2bf(v.x); o.y = f2bf(v.y); o.z = f2bf(v.z); o.w = f2bf(v.w);
    ((u16x4*)xb)[i] = o;
    return;
  }
  blk -= 4096;
  if (blk < 1024) {                     // ---- W transpose -> bf16 (z: Wq,Wk,Wv,Wo)
    int z = blk >> 8, rem = blk & 255;
    int k0 = (rem >> 4) * 64, n0 = (rem & 15) * 64;
    const float* W = z == 0 ? Wq : z == 1 ? Wk : z == 2 ? Wv : Wo;
    unsigned short* out = wt + (size_t)z * E_ * E_;
    float (*tile)[65] = (float(*)[65])smem;
    int r = t >> 2, q4 = t & 3;
#pragma unroll
    for (int q = 0; q < 4; q++) {
      int c4 = q4 + q * 4;
      float4 v = *(const float4*)&W[(size_t)(k0 + r) * E_ + n0 + c4 * 4];
      tile[r][c4 * 4 + 0] = v.x; tile[r][c4 * 4 + 1] = v.y;
      tile[r][c4 * 4 + 2] = v.z; tile[r][c4 * 4 + 3] = v.w;
    }
    __syncthreads();
#pragma unroll
    for (int q = 0; q < 4; q++) {
      int cb = (q4 + q * 4) * 4;
      u16x4 o;
      o.x = f2bf(tile[cb + 0][r]); o.y = f2bf(tile[cb + 1][r]);
      o.z = f2bf(tile[cb + 2][r]); o.w = f2bf(tile[cb + 3][r]);
      *(u16x4*)&out[(size_t)(n0 + r) * E_ + k0 + cb] = o;
    }
    return;
  }
  blk -= 1024;
  if (blk < 260) {                      // ---- rope cos/sin cache
    int i = blk * 256 + t;
    if (i < CT_ * 32) {
      int tt = i >> 5, f = i & 31;
      float invf = __expf(-(float)(2 * f) * (9.210340371976184f / 64.f));  // 10000^(-2f/64)
      float ang = (float)tt * invf;
      cosc[i] = cosf(ang); sinc[i] = sinf(ang);
    }
    return;
  }
  blk -= 260;
  {                                     // ---- router: logits = x @ Wr (256 blocks x 16 rows)
    float* xs = (float*)smem;           // [2][16*16*4] f32, source-swizzled
    float* ws = xs + 2048;              // [2][64*16*4] f32, linear
    int m0 = blk * 16;
    int r = t >> 4, cq = t & 15;
    f32x4 acc = {0.f, 0.f, 0.f, 0.f};

    auto stage = [&](int chunk, int buf) {
      int e0 = chunk * 64;
      gload_lds16(x + (size_t)(m0 + (t >> 4)) * E_ + e0 + (((t & 15) ^ (t >> 4)) << 2),
                  xs + buf * 1024 + t * 4);
#pragma unroll
      for (int j = 0; j < 4; j++) {
        int slot = j * 256 + t;
        gload_lds16(Wr + (size_t)(e0 + (slot >> 4)) * 64 + ((slot & 15) << 2),
                    ws + buf * 4096 + slot * 4);
      }
    };

    stage(0, 0);
    __syncthreads();
    for (int chunk = 0; chunk < 16; chunk++) {
      int cur = chunk & 1;
      if (chunk < 15) stage(chunk + 1, cur ^ 1);
#pragma unroll
      for (int e4 = 0; e4 < 16; e4++) {
        f32x4 xf = *(const f32x4*)(xs + cur * 1024 + (r * 16 + (e4 ^ r)) * 4);
#pragma unroll
        for (int i = 0; i < 4; i++) {
          f32x4 wf = *(const f32x4*)(ws + cur * 4096 + ((e4 * 4 + i) * 16 + cq) * 4);
          acc[0] = fmaf(xf[i], wf[0], acc[0]);
          acc[1] = fmaf(xf[i], wf[1], acc[1]);
          acc[2] = fmaf(xf[i], wf[2], acc[2]);
          acc[3] = fmaf(xf[i], wf[3], acc[3]);
        }
      }
      __syncthreads();
    }
    *(f32x4*)&logits[(size_t)(m0 + r) * 64 + cq * 4] = acc;
  }
}

// ---------------- routing scan, two-phase ----------------
__global__ __launch_bounds__(256) void k_scan1(const float* __restrict__ logits,
    float* __restrict__ probs, unsigned short* __restrict__ pb, float* __restrict__ eposl,
    float* __restrict__ chunkSum) {
  int g = blockIdx.x;
  int bh = g >> 3, c = g & 7;
  int b = bh >> 4, h = bh & 15;
  int t = threadIdx.x;
  int s = c * 256 + t;
  float4 lg = *(const float4*)&logits[(size_t)(b * S_ + s) * 64 + h * 4];
  float m = fmaxf(fmaxf(lg.x, lg.y), fmaxf(lg.z, lg.w));
  float e0 = __expf(lg.x - m), e1 = __expf(lg.y - m), e2 = __expf(lg.z - m), e3 = __expf(lg.w - m);
  float inv = 1.f / (e0 + e1 + e2 + e3);
  float p[4] = {e0 * inv, e1 * inv, e2 * inv, e3 * inv};
  float4 pv; pv.x = p[0]; pv.y = p[1]; pv.z = p[2]; pv.w = p[3];
  *(float4*)&probs[((size_t)bh * S_ + s) * 4] = pv;
  u16x4 pu; pu.x = f2bf(p[0]); pu.y = f2bf(p[1]); pu.z = f2bf(p[2]); pu.w = f2bf(p[3]);
  *(u16x4*)&pb[((size_t)bh * S_ + s) * 4] = pu;

  __shared__ float sc[4][256];
#pragma unroll
  for (int k = 0; k < 4; k++) sc[k][t] = p[k];
  __syncthreads();
  for (int off = 1; off < 256; off <<= 1) {
    float v0 = 0, v1 = 0, v2 = 0, v3 = 0;
    if (t >= off) { v0 = sc[0][t - off]; v1 = sc[1][t - off]; v2 = sc[2][t - off]; v3 = sc[3][t - off]; }
    __syncthreads();
    if (t >= off) { sc[0][t] += v0; sc[1][t] += v1; sc[2][t] += v2; sc[3][t] += v3; }
    __syncthreads();
  }
  float4 ev;
  ev.x = sc[0][t] - p[0]; ev.y = sc[1][t] - p[1];
  ev.z = sc[2][t] - p[2]; ev.w = sc[3][t] - p[3];
  *(float4*)&eposl[((size_t)bh * S_ + s) * 4] = ev;
  if (t == 255) {
    float4 cs; cs.x = sc[0][255]; cs.y = sc[1][255]; cs.z = sc[2][255]; cs.w = sc[3][255];
    *(float4*)&chunkSum[(size_t)(bh * 8 + c) * 4] = cs;
  }
}

__global__ __launch_bounds__(64) void k_scan2(const float* __restrict__ chunkSum,
    float* __restrict__ chunkBase) {
  int bh = threadIdx.x;
  if (bh >= 32) return;
  float r0 = 0.f, r1 = 0.f, r2 = 0.f, r3 = 0.f;
  for (int c = 0; c < 8; c++) {
    float4 cs = *(const float4*)&chunkSum[(size_t)(bh * 8 + c) * 4];
    float4 cb; cb.x = r0; cb.y = r1; cb.z = r2; cb.w = r3;
    *(float4*)&chunkBase[(size_t)(bh * 8 + c) * 4] = cb;
    r0 += cs.x; r1 += cs.y; r2 += cs.z; r3 += cs.w;
  }
}

__global__ __launch_bounds__(256) void k_cwsw(const float* __restrict__ probs,
    const float* __restrict__ eposl, const float* __restrict__ chunkBase,
    const float* __restrict__ cosc, const float* __restrict__ sinc,
    float* __restrict__ cw, float* __restrict__ sw) {
  int bh = blockIdx.y;
  int s = blockIdx.x * 8 + (threadIdx.x >> 5);
  int f = threadIdx.x & 31;
  size_t row = (size_t)bh * S_ + s;
  const float* cb = &chunkBase[(size_t)(bh * 8 + (s >> 8)) * 4];
  float cacc = 0.f, sacc = 0.f;
#pragma unroll
  for (int k = 0; k < 4; k++) {
    float pk = probs[row * 4 + k];
    float pos = eposl[row * 4 + k] + cb[k];
    pos = fminf(fmaxf(pos, 0.f), (float)(CT_ - 2));
    int pf = (int)pos; float fr = pos - (float)pf;
    float c0 = cosc[pf * 32 + f], c1 = cosc[pf * 32 + 32 + f];
    float s0 = sinc[pf * 32 + f], s1 = sinc[pf * 32 + 32 + f];
    cacc = fmaf(pk, c0 + fr * (c1 - c0), cacc);
    sacc = fmaf(pk, s0 + fr * (s1 - s0), sacc);
  }
  cw[row * 32 + f] = cacc; sw[row * 32 + f] = sacc;
}

// ---------------- GEMM mainloop (128x128 tile, BK=64, 4 waves 2x2) ----------------
__device__ __forceinline__ void gemm_128x128(const unsigned short* __restrict__ A,
    const unsigned short* __restrict__ Bt, int m0, int n0,
    unsigned short* lA, unsigned short* lB, f32x4 acc[4][4]) {
  int t = threadIdx.x, w = t >> 6, lane = t & 63;
  int wm = w >> 1, wn = w & 1;
  int arow = lane & 15, agrp = lane >> 4;
  for (int k0 = 0; k0 < E_; k0 += 64) {
    __syncthreads();
#pragma unroll
    for (int j = 0; j < 4; j++) {
      int c = j * 256 + w * 64 + lane;
      int row = c >> 3, slot = c & 7;
      gload_lds16(A + (size_t)(m0 + row) * E_ + k0 + ((slot ^ (row & 7)) << 3),
                  lA + (size_t)(j * 256 + w * 64) * 8);
      gload_lds16(Bt + (size_t)(n0 + row) * E_ + k0 + ((slot ^ (row & 7)) << 3),
                  lB + (size_t)(j * 256 + w * 64) * 8);
    }
    __syncthreads();
#pragma unroll
    for (int ks = 0; ks < 2; ks++) {
      short8 af[4], bfr[4];
#pragma unroll
      for (int mi = 0; mi < 4; mi++) af[mi] = lds8(lA, wm * 64 + mi * 16 + arow, ks * 4 + agrp);
#pragma unroll
      for (int nj = 0; nj < 4; nj++) bfr[nj] = lds8(lB, wn * 64 + nj * 16 + arow, ks * 4 + agrp);
#pragma unroll
      for (int mi = 0; mi < 4; mi++)
#pragma unroll
        for (int nj = 0; nj < 4; nj++)
          acc[mi][nj] = __builtin_amdgcn_mfma_f32_16x16x32_bf16(af[mi], bfr[nj], acc[mi][nj], 0, 0, 0);
    }
  }
}

// q/k/v projections; q,k get fused fractional RoPE in the epilogue (q also gets *SCALE*log2e)
// V is stored TRANSPOSED: vb[bh][d][s]. XCD-bijective swizzle: each XCD owns 4 M-tiles
// (1MB A, shared across z) x all N -> per-XCD L2 working set ~3MB (was: full 8.4MB A).
__global__ __launch_bounds__(256) void k_gemm_qkv(const unsigned short* __restrict__ xb,
    const unsigned short* __restrict__ wt, const float* __restrict__ cw, const float* __restrict__ sw,
    unsigned short* __restrict__ qr, unsigned short* __restrict__ kr, unsigned short* __restrict__ vb) {
  __shared__ unsigned short lA[128 * 64], lB[128 * 64];
  int z = blockIdx.z;
  int id = blockIdx.x + 8 * blockIdx.y;          // [0,256)
  int xcd = id & 7, slot = id >> 3;
  int my = (xcd << 2) | (slot & 3);              // [0,32)
  int nx = slot >> 2;                            // [0,8)
  int m0 = my * 128, n0 = nx * 128;
  f32x4 acc[4][4];
  f32x4 zero4 = {0.f, 0.f, 0.f, 0.f};
#pragma unroll
  for (int a = 0; a < 4; a++)
#pragma unroll
    for (int b2 = 0; b2 < 4; b2++) acc[a][b2] = zero4;
  gemm_128x128(xb, wt + (size_t)z * E_ * E_, m0, n0, lA, lB, acc);

  int t = threadIdx.x, w = t >> 6, lane = t & 63;
  int wm = w >> 1, wn = w & 1;
  int arow = lane & 15, agrp = lane >> 4;
  if (z == 2) {
#pragma unroll
    for (int mi = 0; mi < 4; mi++) {
      int i0 = m0 + wm * 64 + mi * 16 + agrp * 4;
      int b = i0 >> 11, s0 = i0 & 2047;
#pragma unroll
      for (int nj = 0; nj < 4; nj++) {
        int col = n0 + wn * 64 + nj * 16 + arow;
        int h = col >> 6, dl = col & 63;
        u16x4 o;
        o.x = f2bf(acc[mi][nj][0]); o.y = f2bf(acc[mi][nj][1]);
        o.z = f2bf(acc[mi][nj][2]); o.w = f2bf(acc[mi][nj][3]);
        *(u16x4*)&vb[((size_t)(b * H_ + h) * 64 + dl) * S_ + s0] = o;
      }
    }
  } else {
    unsigned short* out = (z == 0) ? qr : kr;
    float scl = (z == 0) ? 0.18033688011f : 1.0f;  // 0.125 * log2(e)
    int h = (n0 + wn * 64) >> 6;
#pragma unroll
    for (int mi = 0; mi < 4; mi++)
#pragma unroll
      for (int reg = 0; reg < 4; reg++) {
        int i = m0 + wm * 64 + mi * 16 + agrp * 4 + reg;
        int b = i >> 11, s = i & 2047;
        size_t rbase = (size_t)(b * H_ + h) * S_ + s;
        float cw0 = cw[rbase * 32 + arow], cw1 = cw[rbase * 32 + 16 + arow];
        float sw0 = sw[rbase * 32 + arow], sw1 = sw[rbase * 32 + 16 + arow];
#pragma unroll
        for (int nj = 0; nj < 4; nj++) {
          float v = acc[mi][nj][reg];
          float part = acc[mi][nj ^ 2][reg];
          float rh = (nj < 2) ? -part : part;      // rotate_half
          float cwv = (nj & 1) ? cw1 : cw0;
          float swv = (nj & 1) ? sw1 : sw0;
          out[rbase * 64 + nj * 16 + arow] = f2bf((v * cwv + rh * swv) * scl);
        }
      }
  }
}

// 64x128-tile output GEMM; XCD-bijective swizzle (each XCD: 8 M-tiles x all N, ~3MB L2 set)
__global__ __launch_bounds__(256) void k_gemm_out(const unsigned short* __restrict__ ob,
    const unsigned short* __restrict__ wot, float* __restrict__ dout) {
  __shared__ unsigned short lA[64 * 64];
  __shared__ unsigned short lB[128 * 64];
  int id = blockIdx.x + 8 * blockIdx.y;          // [0,512)
  int xcd = id & 7, slot = id >> 3;
  int my = (xcd << 3) | (slot & 7);              // [0,64)
  int nx = slot >> 3;                            // [0,8)
  int m0 = my * 64, n0 = nx * 128;
  int t = threadIdx.x, w = t >> 6, lane = t & 63;
  int arow = lane & 15, agrp = lane >> 4;
  f32x4 acc[4][2];
  f32x4 zero4 = {0.f, 0.f, 0.f, 0.f};
#pragma unroll
  for (int a = 0; a < 4; a++) { acc[a][0] = zero4; acc[a][1] = zero4; }
  for (int k0 = 0; k0 < E_; k0 += 64) {
    __syncthreads();
#pragma unroll
    for (int j = 0; j < 2; j++) {
      int c = j * 256 + t;
      int row = c >> 3, slot2 = c & 7;
      gload_lds16(ob + (size_t)(m0 + row) * E_ + k0 + ((slot2 ^ (row & 7)) << 3),
                  lA + (size_t)c * 8);
    }
#pragma unroll
    for (int j = 0; j < 4; j++) {
      int c = j * 256 + t;
      int row = c >> 3, slot2 = c & 7;
      gload_lds16(wot + (size_t)(n0 + row) * E_ + k0 + ((slot2 ^ (row & 7)) << 3),
                  lB + (size_t)c * 8);
    }
    __syncthreads();
#pragma unroll
    for (int ks = 0; ks < 2; ks++) {
      short8 af[4], bfr[2];
#pragma unroll
      for (int mi = 0; mi < 4; mi++) af[mi] = lds8(lA, mi * 16 + arow, ks * 4 + agrp);
#pragma unroll
      for (int nj = 0; nj < 2; nj++) bfr[nj] = lds8(lB, w * 32 + nj * 16 + arow, ks * 4 + agrp);
#pragma unroll
      for (int mi = 0; mi < 4; mi++)
#pragma unroll
        for (int nj = 0; nj < 2; nj++)
          acc[mi][nj] = __builtin_amdgcn_mfma_f32_16x16x32_bf16(af[mi], bfr[nj], acc[mi][nj], 0, 0, 0);
    }
  }
#pragma unroll
  for (int mi = 0; mi < 4; mi++)
#pragma unroll
    for (int reg = 0; reg < 4; reg++) {
      int i = m0 + mi * 16 + agrp * 4 + reg;
#pragma unroll
      for (int nj = 0; nj < 2; nj++) {
        int col = n0 + w * 32 + nj * 16 + arow;
        dout[(size_t)i * E_ + col] = acc[mi][nj][reg];
      }
    }
}

// ---------------- flash attention ----------------
// v9: software-pipelined KV loop. Tile i's softmax (VALU) overlaps tile i+1's QK (MFMA)
// within the wave. Buffer safety per iter (after the top barrier): lK[cur] is dead
// (QK(i) consumed it pre-barrier) -> stage K(i+2) there; lV[cur^1]'s readers PV(i-1)
// are barrier-confirmed done -> stage V(i+1) there; QK(i+1) reads lK[cur^1] (arrival =
// barrier's vmcnt drain); PV(i) reads lV[cur]. One barrier/tile. Double sacc via named
// saccA/saccB + 2-unrolled loop (static indexing, rule #20).
__device__ const int4 kChunk[38] = {
  { 8,0, 8, 8},{ 8,9,17, 9},{12,0, 8,19},{12,9,17,20},
  { 7,0, 7, 6},{ 7,8,15, 7},{10,0, 7,13},{11,0, 7,16},{11,8,15,17},{11,16,23,18},
  {12,18,25,21},{14,0, 7,26},{14,8,15,27},{15,0, 7,30},{15,8,15,31},{15,16,23,32},
  {15,24,31,33},{ 3,0, 7,-1},
  { 6,0, 6, 4},{ 6,7,13, 5},{ 9,0, 6,10},{ 9,7,13,11},{10,8,14,14},{10,15,21,15},
  {13,0, 6,22},{13,7,13,23},{13,14,20,24},{13,21,27,25},{14,16,22,28},{14,23,29,29},
  { 5,0, 5, 2},{ 5,6,11, 3},{ 9,14,19,12},{ 2,0, 5,-1},
  { 4,0, 4, 0},{ 4,5, 9, 1},{ 1,0, 3,-1},{ 0,0, 1,-1}
};

__device__ __forceinline__ short8 mkfrag(u16x4 pv) {
  union { u16x4 v; unsigned u[2]; } pun; pun.v = pv;
  union { short8 s; unsigned u[4]; } z;
  z.u[0] = pun.u[0]; z.u[1] = pun.u[1]; z.u[2] = 0; z.u[3] = 0;
  return z.s;
}

__device__ __forceinline__ void qk_phase2(const char* lKc, const short8 qf[2][2],
    const int kOff[2][4], f32x4 zero4, f32x4 sacc[2][4]) {
#pragma unroll
  for (int ct = 0; ct < 4; ct++) {
    short8 kf = *(const short8*)(lKc + kOff[0][ct]);
    sacc[0][ct] = __builtin_amdgcn_mfma_f32_16x16x32_bf16(qf[0][0], kf, zero4, 0, 0, 0);
    sacc[1][ct] = __builtin_amdgcn_mfma_f32_16x16x32_bf16(qf[1][0], kf, zero4, 0, 0, 0);
  }
#pragma unroll
  for (int ct = 0; ct < 4; ct++) {
    short8 kf = *(const short8*)(lKc + kOff[1][ct]);
    sacc[0][ct] = __builtin_amdgcn_mfma_f32_16x16x32_bf16(qf[0][1], kf, sacc[0][ct], 0, 0, 0);
    sacc[1][ct] = __builtin_amdgcn_mfma_f32_16x16x32_bf16(qf[1][1], kf, sacc[1][ct], 0, 0, 0);
  }
}

__device__ __forceinline__ void softmax_half(const f32x4 sacc[4], const short8 piF,
    const short8 pjF[4], char* lPh, int kv0, int ig_base, int arow, int agrp,
    const int wOff[4][4], float mrow[4], f32x4 oacc[4], f32x4& o4) {
  f32x4 eps4 = {1e-8f, 1e-8f, 1e-8f, 1e-8f};
  f32x4 nwa[4];
#pragma unroll
  for (int ct = 0; ct < 4; ct++)
    nwa[ct] = __builtin_amdgcn_mfma_f32_16x16x32_bf16(piF, pjF[ct], eps4, 0, 0, 0);
  float sv[4][4];
  float rmax[4];
  if (kv0 + 63 > ig_base) {   // tile touches/crosses the diagonal: apply causal mask
#pragma unroll
    for (int ct = 0; ct < 4; ct++) {
      int jg = kv0 + ct * 16 + arow;
#pragma unroll
      for (int reg = 0; reg < 4; reg++) {
        int ig = ig_base + agrp * 4 + reg;
        float xv = sacc[ct][reg];
        if (jg > ig) xv = -1e30f;
        sv[ct][reg] = xv;
      }
    }
  } else {
#pragma unroll
    for (int ct = 0; ct < 4; ct++)
#pragma unroll
      for (int reg = 0; reg < 4; reg++)
        sv[ct][reg] = sacc[ct][reg];
  }
#pragma unroll
  for (int reg = 0; reg < 4; reg++)
    rmax[reg] = redmax16(fmaxf(fmaxf(sv[0][reg], sv[1][reg]), fmaxf(sv[2][reg], sv[3][reg])));
  // defer-max (T13): rescale only when a row's max grew by more than THR (log2 domain).
  bool ok = (rmax[0] <= mrow[0] + 11.5f) & (rmax[1] <= mrow[1] + 11.5f) &
            (rmax[2] <= mrow[2] + 11.5f) & (rmax[3] <= mrow[3] + 11.5f);
  if (!__all(ok)) {
    float alpha[4];
#pragma unroll
    for (int reg = 0; reg < 4; reg++) {
      float mn = fmaxf(mrow[reg], rmax[reg]);
      alpha[reg] = __builtin_amdgcn_exp2f(mrow[reg] - mn);
      mrow[reg] = mn;
    }
#pragma unroll
    for (int dt = 0; dt < 4; dt++) {
      f32x4 o = oacc[dt];
      o.x *= alpha[0]; o.y *= alpha[1]; o.z *= alpha[2]; o.w *= alpha[3];
      oacc[dt] = o;
    }
    o4.x *= alpha[0]; o4.y *= alpha[1]; o4.z *= alpha[2]; o4.w *= alpha[3];
  }
#pragma unroll
  for (int ct = 0; ct < 4; ct++)
#pragma unroll
    for (int reg = 0; reg < 4; reg++)
      sv[ct][reg] = __builtin_amdgcn_exp2f(sv[ct][reg] - mrow[reg]) * nwa[ct][reg];
  // P -> bf16 via packed convert (RNE, same as f2bf)
#pragma unroll
  for (int ct = 0; ct < 4; ct++) {
#pragma unroll
    for (int rp = 0; rp < 2; rp++) {
      unsigned pk;
      asm("v_cvt_pk_bf16_f32 %0, %1, %2" : "=v"(pk) : "v"(sv[ct][rp * 2]), "v"(sv[ct][rp * 2 + 1]));
      *(unsigned short*)(lPh + wOff[ct][rp * 2 + 0]) = (unsigned short)pk;
      *(unsigned short*)(lPh + wOff[ct][rp * 2 + 1]) = (unsigned short)(pk >> 16);
    }
  }
}

__device__ __forceinline__ void pv2(const char* lPw, const char* lVc,
    const int pOff[2], const int kOff[2][4], f32x4 oacc0[4], f32x4 oacc1[4],
    f32x4& o40, f32x4& o41) {
  // ones-column trick: B = all-ones -> every output column = row-sum of P = l.
  const short8 ones = {16256, 16256, 16256, 16256, 16256, 16256, 16256, 16256};  // bf16 1.0
#pragma unroll
  for (int ks = 0; ks < 2; ks++) {
    short8 pf0 = *(const short8*)(lPw + pOff[ks]);
    short8 pf1 = *(const short8*)(lPw + 2048 + pOff[ks]);
    o40 = __builtin_amdgcn_mfma_f32_16x16x32_bf16(pf0, ones, o40, 0, 0, 0);
    o41 = __builtin_amdgcn_mfma_f32_16x16x32_bf16(pf1, ones, o41, 0, 0, 0);
#pragma unroll
    for (int dt = 0; dt < 4; dt++) {
      short8 vf = *(const short8*)(lVc + kOff[ks][dt]);
      oacc0[dt] = __builtin_amdgcn_mfma_f32_16x16x32_bf16(pf0, vf, oacc0[dt], 0, 0, 0);
      oacc1[dt] = __builtin_amdgcn_mfma_f32_16x16x32_bf16(pf1, vf, oacc1[dt], 0, 0, 0);
    }
  }
}

__global__ __launch_bounds__(256, 2) void k_attn(const unsigned short* __restrict__ qr,
    const unsigned short* __restrict__ kr, const unsigned short* __restrict__ vb,
    const unsigned short* __restrict__ pb, unsigned short* __restrict__ ob,
    unsigned short* __restrict__ ObP, float* __restrict__ ml) {
  __shared__ unsigned short lK[2][64 * 64];
  __shared__ unsigned short lV[2][64 * 64];     // V^T tile, staged like K
  __shared__ unsigned short lP[4][2][16 * 64];  // per-wave, per-half P staging
  int id = blockIdx.x;
  int xcd = id & 7, slt = id >> 3;
  int bh = xcd * 4 + (slt & 3);
  int4 ck = kChunk[slt >> 2];
  int qt2 = ck.x, j0 = ck.y, j1 = ck.z, part = ck.w;
  int t = threadIdx.x, w = t >> 6, lane = t & 63;
  int arow = lane & 15, agrp = lane >> 4;
  int q0 = qt2 * 128;
  size_t base = (size_t)bh * S_ * 64;   // also the V^T base: bh*64*S
  size_t bhS = (size_t)bh * S_;

  // ---- hoisted LDS offsets (loop-invariant) ----
  int kOff[2][4], pOff[2], wOff[4][4];
#pragma unroll
  for (int ks = 0; ks < 2; ks++) {
    pOff[ks] = arow * 128 + (((ks * 4 + agrp) ^ (arow & 7)) << 4);
#pragma unroll
    for (int ct = 0; ct < 4; ct++) {
      int row = ct * 16 + arow;
      kOff[ks][ct] = row * 128 + (((ks * 4 + agrp) ^ (row & 7)) << 4);
    }
  }
#pragma unroll
  for (int ct = 0; ct < 4; ct++) {
    int col2 = (ct * 16 + arow) * 2;
#pragma unroll
    for (int rr = 0; rr < 4; rr++) {
      int r = agrp * 4 + rr;
      wOff[ct][rr] = r * 128 + (col2 ^ ((r & 7) << 4));
    }
  }

  // ---- hoisted per-lane global pointers (element units) ----
  const unsigned short* kSrc[2];
  const unsigned short* vSrc[2];
  unsigned short* kDst[2];
  unsigned short* vDst[2];
#pragma unroll
  for (int j = 0; j < 2; j++) {
    int c = j * 256 + w * 64 + lane;
    int row = c >> 3, slot = c & 7;
    kSrc[j] = kr + base + (size_t)row * 64 + ((slot ^ (row & 7)) << 3);
    vSrc[j] = vb + base + (size_t)row * S_ + ((slot ^ (row & 7)) << 3);
    kDst[j] = &lK[0][(j * 256 + w * 64) * 8];
    vDst[j] = &lV[0][(j * 256 + w * 64) * 8];
  }
  const unsigned short* pjSrc[4];
#pragma unroll
  for (int ct = 0; ct < 4; ct++) pjSrc[ct] = pb + (bhS + ct * 16 + arow) * 4;

  short8 qf[2][2];
  short8 piF[2];
  float mrow[2][4];
  f32x4 oacc[2][4];
  f32x4 o4[2];
  f32x4 zero4 = {0.f, 0.f, 0.f, 0.f};
#pragma unroll
  for (int hh = 0; hh < 2; hh++) {
#pragma unroll
    for (int ks = 0; ks < 2; ks++)
      qf[hh][ks] = *(const short8*)&qr[base + (size_t)(q0 + hh * 64 + w * 16 + arow) * 64 + ks * 32 + agrp * 8];
    u16x4 pv = {0, 0, 0, 0};
    if (agrp == 0) pv = *(const u16x4*)&pb[(bhS + q0 + hh * 64 + w * 16 + arow) * 4];
    piF[hh] = mkfrag(pv);
#pragma unroll
    for (int reg = 0; reg < 4; reg++) mrow[hh][reg] = -1e30f;
#pragma unroll
    for (int dt = 0; dt < 4; dt++) oacc[hh][dt] = zero4;
    o4[hh] = zero4;
  }

  auto stageK = [&](int jt, int buf) {
#pragma unroll
    for (int j = 0; j < 2; j++)
      gload_lds16(kSrc[j] + jt * 4096, kDst[j] + buf * 4096);
  };
  auto stageV = [&](int jt, int buf) {
#pragma unroll
    for (int j = 0; j < 2; j++)
      gload_lds16(vSrc[j] + jt * 64, vDst[j] + buf * 4096);
  };
  auto loadPj = [&](int jt, u16x4 pj[4]) {
#pragma unroll
    for (int ct = 0; ct < 4; ct++) {
      u16x4 z = {0, 0, 0, 0};
      if (agrp == 0) z = *(const u16x4*)(pjSrc[ct] + jt * 256);
      pj[ct] = z;
    }
  };

  char* lPw = (char*)&lP[w][0][0];
  int nt = j1 - j0 + 1;

  f32x4 saccA[2][4], saccB[2][4];
  u16x4 pjvA[4], pjvB[4];

  // prologue: stage K(0),V(0) -> buf0, K(1) -> buf1; barrier; QK(0)
  stageK(j0, 0);
  stageV(j0, 0);
  if (nt > 1) stageK(j0 + 1, 1);
  loadPj(j0, pjvA);
  __syncthreads();
  qk_phase2((const char*)lK, qf, kOff, zero4, saccA);

  // pipelined body: per iter i -- barrier; stage K(i+2)->lK[cur], V(i+1)->lV[cur^1];
  // QK(i+1) (MFMA) || softmax(i) (VALU); fence; PV(i).
#define ATTN_BODY(i_, scC, scN, pjC, pjN)                                       \
  {                                                                             \
    int cur = (i_) & 1;                                                         \
    int kv0 = (j0 + (i_)) * 64;                                                 \
    __syncthreads();                                                            \
    if ((i_) + 2 < nt) stageK(j0 + (i_) + 2, cur);                              \
    if ((i_) + 1 < nt) {                                                        \
      stageV(j0 + (i_) + 1, cur ^ 1);                                           \
      qk_phase2((const char*)lK + (cur ^ 1) * 8192, qf, kOff, zero4, scN);      \
    }                                                                           \
    short8 pjF[4];                                                              \
    _Pragma("unroll")                                                           \
    for (int ct = 0; ct < 4; ct++) pjF[ct] = mkfrag(pjC[ct]);                   \
    _Pragma("unroll")                                                           \
    for (int hh = 0; hh < 2; hh++)                                              \
      softmax_half(scC[hh], piF[hh], pjF, lPw + hh * 2048, kv0,                 \
                   q0 + hh * 64 + w * 16, arow, agrp, wOff, mrow[hh],           \
                   oacc[hh], o4[hh]);                                           \
    if ((i_) + 1 < nt) loadPj(j0 + (i_) + 1, pjN);                              \
    asm volatile("s_waitcnt lgkmcnt(0)" ::: "memory");                          \
    __builtin_amdgcn_sched_barrier(0);                                          \
    __builtin_amdgcn_s_setprio(1);                                              \
    pv2(lPw, (const char*)lV + cur * 8192, pOff, kOff, oacc[0], oacc[1],        \
        o4[0], o4[1]);                                                          \
    __builtin_amdgcn_s_setprio(0);                                              \
  }

  {
    int i = 0;
    for (;;) {
      ATTN_BODY(i, saccA, saccB, pjvA, pjvB);
      if (++i >= nt) break;
      ATTN_BODY(i, saccB, saccA, pjvB, pjvA);
      if (++i >= nt) break;
    }
  }
#undef ATTN_BODY

  if (part >= 0) {
    unsigned short* Op = ObP + ((size_t)bh * 34 + part) * 8192;
    float* mlp = ml + ((size_t)bh * 34 + part) * 256;
#pragma unroll
    for (int hh = 0; hh < 2; hh++) {
#pragma unroll
      for (int dt = 0; dt < 4; dt++)
#pragma unroll
        for (int reg = 0; reg < 4; reg++) {
          int row = hh * 64 + w * 16 + agrp * 4 + reg;
          Op[row * 64 + dt * 16 + arow] = f2bf(oacc[hh][dt][reg]);
        }
      if (arow == 0) {
#pragma unroll
        for (int reg = 0; reg < 4; reg++) {
          int row = hh * 64 + w * 16 + agrp * 4 + reg;
          mlp[row] = mrow[hh][reg];
          mlp[128 + row] = o4[hh][reg];   // l from the ones-column accumulator
        }
      }
    }
  } else {
    int b = bh >> 4, h8 = bh & 15;
#pragma unroll
    for (int hh = 0; hh < 2; hh++) {
      f32x4 inv4;
      inv4.x = 1.f / o4[hh].x; inv4.y = 1.f / o4[hh].y;
      inv4.z = 1.f / o4[hh].z; inv4.w = 1.f / o4[hh].w;
#pragma unroll
      for (int dt = 0; dt < 4; dt++)
#pragma unroll
        for (int reg = 0; reg < 4; reg++) {
          int i = q0 + hh * 64 + w * 16 + agrp * 4 + reg;
          int d = dt * 16 + arow;
          float v = oacc[hh][dt][reg] * inv4[reg];
          ob[((size_t)(b * S_ + i) * H_ + h8) * 64 + d] = f2bf(v);
        }
    }
  }
}

__global__ __launch_bounds__(256) void k_merge(const unsigned short* __restrict__ ObP,
    const float* __restrict__ ml, unsigned short* __restrict__ ob) {
  int qx = blockIdx.x, bh = blockIdx.y;
  int qt2 = 4 + qx;
  int np = qt2 <= 8 ? 2 : (qt2 <= 12 ? 3 : 4);
  int bslot = qt2 <= 8 ? (qt2 - 4) * 2 : (qt2 <= 12 ? 10 + (qt2 - 9) * 3 : 22 + (qt2 - 13) * 4);
  int t = threadIdx.x;
  int r = t >> 1, dh = (t & 1) * 32;
  float mp[4], lp[4];
  float m = -1e30f;
  for (int p2 = 0; p2 < np; p2++) {
    const float* mlp = ml + ((size_t)bh * 34 + bslot + p2) * 256;
    mp[p2] = mlp[r]; lp[p2] = mlp[128 + r];
    m = fmaxf(m, mp[p2]);
  }
  float a[4], l = 0.f;
  for (int p2 = 0; p2 < np; p2++) { a[p2] = __builtin_amdgcn_exp2f(mp[p2] - m); l = fmaf(lp[p2], a[p2], l); }
  float inv = 1.f / l;
  for (int p2 = 0; p2 < np; p2++) a[p2] *= inv;
  int i = qt2 * 128 + r, b = bh >> 4, h = bh & 15;
  unsigned short* op = ob + ((size_t)(b * S_ + i) * H_ + h) * 64 + dh;
#pragma unroll
  for (int q = 0; q < 8; q++) {
    float a0 = 0.f, a1 = 0.f, a2 = 0.f, a3 = 0.f;
    for (int p2 = 0; p2 < np; p2++) {
      const unsigned short* Op = ObP + ((size_t)bh * 34 + bslot + p2) * 8192 + r * 64 + dh + q * 4;
      u16x4 xx = *(const u16x4*)Op;
      a0 = fmaf(bf2f(xx.x), a[p2], a0);
      a1 = fmaf(bf2f(xx.y), a[p2], a1);
      a2 = fmaf(bf2f(xx.z), a[p2], a2);
      a3 = fmaf(bf2f(xx.w), a[p2], a3);
    }
    u16x4 o; o.x = f2bf(a0); o.y = f2bf(a1); o.z = f2bf(a2); o.w = f2bf(a3);
    *(u16x4*)(op + q * 4) = o;
  }
}

extern "C" void kernel_launch(void* const* d_in, const int* in_sizes, int n_in,
                              void* d_out, int out_size, void* d_ws, size_t ws_size,
                              hipStream_t stream) {
  const float* x  = (const float*)d_in[0];
  const float* Wq = (const float*)d_in[1];
  const float* Wk = (const float*)d_in[2];
  const float* Wv = (const float*)d_in[3];
  const float* Wr = (const float*)d_in[4];
  const float* Wo = (const float*)d_in[5];
  float* dout = (float*)d_out;

  char* p = (char*)d_ws;
  auto alloc = [&](size_t bytes) -> char* {
    char* r = p; p += (bytes + 255) & ~(size_t)255; return r;
  };
  unsigned short* xb   = (unsigned short*)alloc((size_t)BS_ * E_ * 2);     // dead after qkv
  unsigned short* wt   = (unsigned short*)alloc((size_t)4 * E_ * E_ * 2);
  float* cosc          = (float*)alloc((size_t)CT_ * 32 * 4);
  float* sinc          = (float*)alloc((size_t)CT_ * 32 * 4);
  float* probs         = (float*)alloc((size_t)BH_ * S_ * 4 * 4);
  unsigned short* pb   = (unsigned short*)alloc((size_t)BH_ * S_ * 4 * 2); // bf16 probs
  // the next 4 buffers (18 MB contiguous) are dead by k_attn time -> reused for partials
  float* logits        = (float*)alloc((size_t)BS_ * 64 * 4);
  float* epos          = (float*)alloc((size_t)BH_ * S_ * 4 * 4);
  float* cw            = (float*)alloc((size_t)BH_ * S_ * 32 * 4);
  float* sw            = (float*)alloc((size_t)BH_ * S_ * 32 * 4);
  unsigned short* qrb  = (unsigned short*)alloc((size_t)BH_ * S_ * 64 * 2);
  unsigned short* krb  = (unsigned short*)alloc((size_t)BH_ * S_ * 64 * 2);
  unsigned short* vbb  = (unsigned short*)alloc((size_t)BH_ * S_ * 64 * 2); // V^T [bh][d][s]
  unsigned short* obb  = (unsigned short*)alloc((size_t)BS_ * E_ * 2);
  float* chunkSum      = (float*)alloc((size_t)BH_ * 8 * 4 * 4);
  float* chunkBase     = (float*)alloc((size_t)BH_ * 8 * 4 * 4);
  if ((size_t)(p - (char*)d_ws) > ws_size) return;  // workspace too small -> visible failure

  // partials: bf16 O (34 slots) in the 18 MB dead span; f32 m/l aliased onto dead xb
  unsigned short* ObP = (unsigned short*)logits;      // 32*34*8192 u16 = 17.8 MB
  float* mlbuf = (float*)xb;                          // 32*34*256 f32 = 1.1 MB (xb dead)

  k_prep<<<4096 + 1024 + 260 + 256, 256, 0, stream>>>(x, Wq, Wk, Wv, Wo, Wr,
                                                      xb, wt, cosc, sinc, logits);
  k_scan1<<<BH_ * 8, 256, 0, stream>>>(logits, probs, pb, epos, chunkSum);
  k_scan2<<<1, 64, 0, stream>>>(chunkSum, chunkBase);
  k_cwsw<<<dim3(S_ / 8, BH_), 256, 0, stream>>>(probs, epos, chunkBase, cosc, sinc, cw, sw);
  k_gemm_qkv<<<dim3(8, 32, 3), 256, 0, stream>>>(xb, wt, cw, sw, qrb, krb, vbb);
  k_attn<<<dim3(38 * BH_), 256, 0, stream>>>(qrb, krb, vbb, pb, obb, ObP, mlbuf);
  k_merge<<<dim3(12, BH_), 256, 0, stream>>>(ObP, mlbuf, obb);
  k_gemm_out<<<dim3(8, 64), 256, 0, stream>>>(obb, wt + (size_t)3 * E_ * E_, dout);
}

// Round 10
// 187.398 us; speedup vs baseline: 1.0750x; 1.0750x over previous
//
#include <hip/hip_runtime.h>

#define E_ 1024
#define H_ 16
#define D_ 64
#define K_ 4
#define S_ 2048
#define B_ 2
#define BS_ 4096
#define BH_ 32
#define CT_ 2080

typedef __attribute__((ext_vector_type(8))) short short8;
typedef __attribute__((ext_vector_type(4))) float f32x4;
typedef __attribute__((ext_vector_type(4))) unsigned short u16x4;

__device__ __forceinline__ unsigned short f2bf(float f) {
  union { float f; unsigned u; } v; v.f = f;
  unsigned r = v.u + 0x7FFFu + ((v.u >> 16) & 1u);
  return (unsigned short)(r >> 16);
}
__device__ __forceinline__ float bf2f(unsigned short u) {
  union { unsigned u; float f; } v; v.u = ((unsigned)u) << 16; return v.f;
}

typedef __attribute__((address_space(1))) const void gvoid;
typedef __attribute__((address_space(3))) void lvoid;
__device__ __forceinline__ void gload_lds16(const void* g, void* l) {
  __builtin_amdgcn_global_load_lds((gvoid*)g, (lvoid*)l, 16, 0, 0);
}

// swizzled LDS read: 128B rows, 8 x 16B chunks, chunk ^= (row&7)
__device__ __forceinline__ short8 lds8(const unsigned short* base, int row, int chunk) {
  int off = row * 128 + (((chunk ^ (row & 7)) & 7) << 4);
  return *(const short8*)((const char*)base + off);
}

// 16-lane max reduce: xor1/xor2 via DPP quad_perm, xor4/8 via shfl (proven form)
__device__ __forceinline__ float redmax16(float v) {
  int iv = __float_as_int(v);
  v = fmaxf(v, __int_as_float(__builtin_amdgcn_update_dpp(iv, iv, 0xB1, 0xF, 0xF, true)));
  iv = __float_as_int(v);
  v = fmaxf(v, __int_as_float(__builtin_amdgcn_update_dpp(iv, iv, 0x4E, 0xF, 0xF, true)));
  v = fmaxf(v, __shfl_xor(v, 4, 16));
  v = fmaxf(v, __shfl_xor(v, 8, 16));
  return v;
}

// ---------------- fused prep: convert_x + transpose_w + rope cache + router ----------------
__global__ __launch_bounds__(256) void k_prep(const float* __restrict__ x,
    const float* __restrict__ Wq, const float* __restrict__ Wk, const float* __restrict__ Wv,
    const float* __restrict__ Wo, const float* __restrict__ Wr,
    unsigned short* __restrict__ xb, unsigned short* __restrict__ wt,
    float* __restrict__ cosc, float* __restrict__ sinc, float* __restrict__ logits) {
  __shared__ __align__(16) char smem[40960];
  int blk = blockIdx.x;
  int t = threadIdx.x;

  if (blk < 4096) {                     // ---- x -> bf16
    int i = blk * 256 + t;
    float4 v = ((const float4*)x)[i];
    u16x4 o; o.x = f2bf(v.x); o.y = f2bf(v.y); o.z = f2bf(v.z); o.w = f2bf(v.w);
    ((u16x4*)xb)[i] = o;
    return;
  }
  blk -= 4096;
  if (blk < 1024) {                     // ---- W transpose -> bf16 (z: Wq,Wk,Wv,Wo)
    int z = blk >> 8, rem = blk & 255;
    int k0 = (rem >> 4) * 64, n0 = (rem & 15) * 64;
    const float* W = z == 0 ? Wq : z == 1 ? Wk : z == 2 ? Wv : Wo;
    unsigned short* out = wt + (size_t)z * E_ * E_;
    float (*tile)[65] = (float(*)[65])smem;
    int r = t >> 2, q4 = t & 3;
#pragma unroll
    for (int q = 0; q < 4; q++) {
      int c4 = q4 + q * 4;
      float4 v = *(const float4*)&W[(size_t)(k0 + r) * E_ + n0 + c4 * 4];
      tile[r][c4 * 4 + 0] = v.x; tile[r][c4 * 4 + 1] = v.y;
      tile[r][c4 * 4 + 2] = v.z; tile[r][c4 * 4 + 3] = v.w;
    }
    __syncthreads();
#pragma unroll
    for (int q = 0; q < 4; q++) {
      int cb = (q4 + q * 4) * 4;
      u16x4 o;
      o.x = f2bf(tile[cb + 0][r]); o.y = f2bf(tile[cb + 1][r]);
      o.z = f2bf(tile[cb + 2][r]); o.w = f2bf(tile[cb + 3][r]);
      *(u16x4*)&out[(size_t)(n0 + r) * E_ + k0 + cb] = o;
    }
    return;
  }
  blk -= 1024;
  if (blk < 260) {                      // ---- rope cos/sin cache
    int i = blk * 256 + t;
    if (i < CT_ * 32) {
      int tt = i >> 5, f = i & 31;
      float invf = __expf(-(float)(2 * f) * (9.210340371976184f / 64.f));  // 10000^(-2f/64)
      float ang = (float)tt * invf;
      cosc[i] = cosf(ang); sinc[i] = sinf(ang);
    }
    return;
  }
  blk -= 260;
  {                                     // ---- router: logits = x @ Wr (256 blocks x 16 rows)
    float* xs = (float*)smem;           // [2][16*16*4] f32, source-swizzled
    float* ws = xs + 2048;              // [2][64*16*4] f32, linear
    int m0 = blk * 16;
    int r = t >> 4, cq = t & 15;
    f32x4 acc = {0.f, 0.f, 0.f, 0.f};

    auto stage = [&](int chunk, int buf) {
      int e0 = chunk * 64;
      gload_lds16(x + (size_t)(m0 + (t >> 4)) * E_ + e0 + (((t & 15) ^ (t >> 4)) << 2),
                  xs + buf * 1024 + t * 4);
#pragma unroll
      for (int j = 0; j < 4; j++) {
        int slot = j * 256 + t;
        gload_lds16(Wr + (size_t)(e0 + (slot >> 4)) * 64 + ((slot & 15) << 2),
                    ws + buf * 4096 + slot * 4);
      }
    };

    stage(0, 0);
    __syncthreads();
    for (int chunk = 0; chunk < 16; chunk++) {
      int cur = chunk & 1;
      if (chunk < 15) stage(chunk + 1, cur ^ 1);
#pragma unroll
      for (int e4 = 0; e4 < 16; e4++) {
        f32x4 xf = *(const f32x4*)(xs + cur * 1024 + (r * 16 + (e4 ^ r)) * 4);
#pragma unroll
        for (int i = 0; i < 4; i++) {
          f32x4 wf = *(const f32x4*)(ws + cur * 4096 + ((e4 * 4 + i) * 16 + cq) * 4);
          acc[0] = fmaf(xf[i], wf[0], acc[0]);
          acc[1] = fmaf(xf[i], wf[1], acc[1]);
          acc[2] = fmaf(xf[i], wf[2], acc[2]);
          acc[3] = fmaf(xf[i], wf[3], acc[3]);
        }
      }
      __syncthreads();
    }
    *(f32x4*)&logits[(size_t)(m0 + r) * 64 + cq * 4] = acc;
  }
}

// ---------------- routing scan, two-phase ----------------
__global__ __launch_bounds__(256) void k_scan1(const float* __restrict__ logits,
    float* __restrict__ probs, unsigned short* __restrict__ pb, float* __restrict__ eposl,
    float* __restrict__ chunkSum) {
  int g = blockIdx.x;
  int bh = g >> 3, c = g & 7;
  int b = bh >> 4, h = bh & 15;
  int t = threadIdx.x;
  int s = c * 256 + t;
  float4 lg = *(const float4*)&logits[(size_t)(b * S_ + s) * 64 + h * 4];
  float m = fmaxf(fmaxf(lg.x, lg.y), fmaxf(lg.z, lg.w));
  float e0 = __expf(lg.x - m), e1 = __expf(lg.y - m), e2 = __expf(lg.z - m), e3 = __expf(lg.w - m);
  float inv = 1.f / (e0 + e1 + e2 + e3);
  float p[4] = {e0 * inv, e1 * inv, e2 * inv, e3 * inv};
  float4 pv; pv.x = p[0]; pv.y = p[1]; pv.z = p[2]; pv.w = p[3];
  *(float4*)&probs[((size_t)bh * S_ + s) * 4] = pv;
  u16x4 pu; pu.x = f2bf(p[0]); pu.y = f2bf(p[1]); pu.z = f2bf(p[2]); pu.w = f2bf(p[3]);
  *(u16x4*)&pb[((size_t)bh * S_ + s) * 4] = pu;

  __shared__ float sc[4][256];
#pragma unroll
  for (int k = 0; k < 4; k++) sc[k][t] = p[k];
  __syncthreads();
  for (int off = 1; off < 256; off <<= 1) {
    float v0 = 0, v1 = 0, v2 = 0, v3 = 0;
    if (t >= off) { v0 = sc[0][t - off]; v1 = sc[1][t - off]; v2 = sc[2][t - off]; v3 = sc[3][t - off]; }
    __syncthreads();
    if (t >= off) { sc[0][t] += v0; sc[1][t] += v1; sc[2][t] += v2; sc[3][t] += v3; }
    __syncthreads();
  }
  float4 ev;
  ev.x = sc[0][t] - p[0]; ev.y = sc[1][t] - p[1];
  ev.z = sc[2][t] - p[2]; ev.w = sc[3][t] - p[3];
  *(float4*)&eposl[((size_t)bh * S_ + s) * 4] = ev;
  if (t == 255) {
    float4 cs; cs.x = sc[0][255]; cs.y = sc[1][255]; cs.z = sc[2][255]; cs.w = sc[3][255];
    *(float4*)&chunkSum[(size_t)(bh * 8 + c) * 4] = cs;
  }
}

__global__ __launch_bounds__(64) void k_scan2(const float* __restrict__ chunkSum,
    float* __restrict__ chunkBase) {
  int bh = threadIdx.x;
  if (bh >= 32) return;
  float r0 = 0.f, r1 = 0.f, r2 = 0.f, r3 = 0.f;
  for (int c = 0; c < 8; c++) {
    float4 cs = *(const float4*)&chunkSum[(size_t)(bh * 8 + c) * 4];
    float4 cb; cb.x = r0; cb.y = r1; cb.z = r2; cb.w = r3;
    *(float4*)&chunkBase[(size_t)(bh * 8 + c) * 4] = cb;
    r0 += cs.x; r1 += cs.y; r2 += cs.z; r3 += cs.w;
  }
}

__global__ __launch_bounds__(256) void k_cwsw(const float* __restrict__ probs,
    const float* __restrict__ eposl, const float* __restrict__ chunkBase,
    const float* __restrict__ cosc, const float* __restrict__ sinc,
    float* __restrict__ cw, float* __restrict__ sw) {
  int bh = blockIdx.y;
  int s = blockIdx.x * 8 + (threadIdx.x >> 5);
  int f = threadIdx.x & 31;
  size_t row = (size_t)bh * S_ + s;
  const float* cb = &chunkBase[(size_t)(bh * 8 + (s >> 8)) * 4];
  float cacc = 0.f, sacc = 0.f;
#pragma unroll
  for (int k = 0; k < 4; k++) {
    float pk = probs[row * 4 + k];
    float pos = eposl[row * 4 + k] + cb[k];
    pos = fminf(fmaxf(pos, 0.f), (float)(CT_ - 2));
    int pf = (int)pos; float fr = pos - (float)pf;
    float c0 = cosc[pf * 32 + f], c1 = cosc[pf * 32 + 32 + f];
    float s0 = sinc[pf * 32 + f], s1 = sinc[pf * 32 + 32 + f];
    cacc = fmaf(pk, c0 + fr * (c1 - c0), cacc);
    sacc = fmaf(pk, s0 + fr * (s1 - s0), sacc);
  }
  cw[row * 32 + f] = cacc; sw[row * 32 + f] = sacc;
}

// ---------------- GEMM mainloop (128x128 tile, BK=64, 4 waves 2x2) ----------------
__device__ __forceinline__ void gemm_128x128(const unsigned short* __restrict__ A,
    const unsigned short* __restrict__ Bt, int m0, int n0,
    unsigned short* lA, unsigned short* lB, f32x4 acc[4][4]) {
  int t = threadIdx.x, w = t >> 6, lane = t & 63;
  int wm = w >> 1, wn = w & 1;
  int arow = lane & 15, agrp = lane >> 4;
  for (int k0 = 0; k0 < E_; k0 += 64) {
    __syncthreads();
#pragma unroll
    for (int j = 0; j < 4; j++) {
      int c = j * 256 + w * 64 + lane;
      int row = c >> 3, slot = c & 7;
      gload_lds16(A + (size_t)(m0 + row) * E_ + k0 + ((slot ^ (row & 7)) << 3),
                  lA + (size_t)(j * 256 + w * 64) * 8);
      gload_lds16(Bt + (size_t)(n0 + row) * E_ + k0 + ((slot ^ (row & 7)) << 3),
                  lB + (size_t)(j * 256 + w * 64) * 8);
    }
    __syncthreads();
#pragma unroll
    for (int ks = 0; ks < 2; ks++) {
      short8 af[4], bfr[4];
#pragma unroll
      for (int mi = 0; mi < 4; mi++) af[mi] = lds8(lA, wm * 64 + mi * 16 + arow, ks * 4 + agrp);
#pragma unroll
      for (int nj = 0; nj < 4; nj++) bfr[nj] = lds8(lB, wn * 64 + nj * 16 + arow, ks * 4 + agrp);
#pragma unroll
      for (int mi = 0; mi < 4; mi++)
#pragma unroll
        for (int nj = 0; nj < 4; nj++)
          acc[mi][nj] = __builtin_amdgcn_mfma_f32_16x16x32_bf16(af[mi], bfr[nj], acc[mi][nj], 0, 0, 0);
    }
  }
}

// q/k/v projections; q,k get fused fractional RoPE in the epilogue (q also gets *SCALE*log2e)
// V is stored TRANSPOSED: vb[bh][d][s]. XCD-bijective swizzle: each XCD owns 4 M-tiles
// (1MB A, shared across z) x all N -> per-XCD L2 working set ~3MB (kept from R9: ~6us gain).
__global__ __launch_bounds__(256) void k_gemm_qkv(const unsigned short* __restrict__ xb,
    const unsigned short* __restrict__ wt, const float* __restrict__ cw, const float* __restrict__ sw,
    unsigned short* __restrict__ qr, unsigned short* __restrict__ kr, unsigned short* __restrict__ vb) {
  __shared__ unsigned short lA[128 * 64], lB[128 * 64];
  int z = blockIdx.z;
  int id = blockIdx.x + 8 * blockIdx.y;          // [0,256)
  int xcd = id & 7, slot = id >> 3;
  int my = (xcd << 2) | (slot & 3);              // [0,32)
  int nx = slot >> 2;                            // [0,8)
  int m0 = my * 128, n0 = nx * 128;
  f32x4 acc[4][4];
  f32x4 zero4 = {0.f, 0.f, 0.f, 0.f};
#pragma unroll
  for (int a = 0; a < 4; a++)
#pragma unroll
    for (int b2 = 0; b2 < 4; b2++) acc[a][b2] = zero4;
  gemm_128x128(xb, wt + (size_t)z * E_ * E_, m0, n0, lA, lB, acc);

  int t = threadIdx.x, w = t >> 6, lane = t & 63;
  int wm = w >> 1, wn = w & 1;
  int arow = lane & 15, agrp = lane >> 4;
  if (z == 2) {
#pragma unroll
    for (int mi = 0; mi < 4; mi++) {
      int i0 = m0 + wm * 64 + mi * 16 + agrp * 4;
      int b = i0 >> 11, s0 = i0 & 2047;
#pragma unroll
      for (int nj = 0; nj < 4; nj++) {
        int col = n0 + wn * 64 + nj * 16 + arow;
        int h = col >> 6, dl = col & 63;
        u16x4 o;
        o.x = f2bf(acc[mi][nj][0]); o.y = f2bf(acc[mi][nj][1]);
        o.z = f2bf(acc[mi][nj][2]); o.w = f2bf(acc[mi][nj][3]);
        *(u16x4*)&vb[((size_t)(b * H_ + h) * 64 + dl) * S_ + s0] = o;
      }
    }
  } else {
    unsigned short* out = (z == 0) ? qr : kr;
    float scl = (z == 0) ? 0.18033688011f : 1.0f;  // 0.125 * log2(e)
    int h = (n0 + wn * 64) >> 6;
#pragma unroll
    for (int mi = 0; mi < 4; mi++)
#pragma unroll
      for (int reg = 0; reg < 4; reg++) {
        int i = m0 + wm * 64 + mi * 16 + agrp * 4 + reg;
        int b = i >> 11, s = i & 2047;
        size_t rbase = (size_t)(b * H_ + h) * S_ + s;
        float cw0 = cw[rbase * 32 + arow], cw1 = cw[rbase * 32 + 16 + arow];
        float sw0 = sw[rbase * 32 + arow], sw1 = sw[rbase * 32 + 16 + arow];
#pragma unroll
        for (int nj = 0; nj < 4; nj++) {
          float v = acc[mi][nj][reg];
          float part = acc[mi][nj ^ 2][reg];
          float rh = (nj < 2) ? -part : part;      // rotate_half
          float cwv = (nj & 1) ? cw1 : cw0;
          float swv = (nj & 1) ? sw1 : sw0;
          out[rbase * 64 + nj * 16 + arow] = f2bf((v * cwv + rh * swv) * scl);
        }
      }
  }
}

// 64x128-tile output GEMM; XCD-bijective swizzle (each XCD: 8 M-tiles x all N, ~3MB L2 set)
__global__ __launch_bounds__(256) void k_gemm_out(const unsigned short* __restrict__ ob,
    const unsigned short* __restrict__ wot, float* __restrict__ dout) {
  __shared__ unsigned short lA[64 * 64];
  __shared__ unsigned short lB[128 * 64];
  int id = blockIdx.x + 8 * blockIdx.y;          // [0,512)
  int xcd = id & 7, slot = id >> 3;
  int my = (xcd << 3) | (slot & 7);              // [0,64)
  int nx = slot >> 3;                            // [0,8)
  int m0 = my * 64, n0 = nx * 128;
  int t = threadIdx.x, w = t >> 6, lane = t & 63;
  int arow = lane & 15, agrp = lane >> 4;
  f32x4 acc[4][2];
  f32x4 zero4 = {0.f, 0.f, 0.f, 0.f};
#pragma unroll
  for (int a = 0; a < 4; a++) { acc[a][0] = zero4; acc[a][1] = zero4; }
  for (int k0 = 0; k0 < E_; k0 += 64) {
    __syncthreads();
#pragma unroll
    for (int j = 0; j < 2; j++) {
      int c = j * 256 + t;
      int row = c >> 3, slot2 = c & 7;
      gload_lds16(ob + (size_t)(m0 + row) * E_ + k0 + ((slot2 ^ (row & 7)) << 3),
                  lA + (size_t)c * 8);
    }
#pragma unroll
    for (int j = 0; j < 4; j++) {
      int c = j * 256 + t;
      int row = c >> 3, slot2 = c & 7;
      gload_lds16(wot + (size_t)(n0 + row) * E_ + k0 + ((slot2 ^ (row & 7)) << 3),
                  lB + (size_t)c * 8);
    }
    __syncthreads();
#pragma unroll
    for (int ks = 0; ks < 2; ks++) {
      short8 af[4], bfr[2];
#pragma unroll
      for (int mi = 0; mi < 4; mi++) af[mi] = lds8(lA, mi * 16 + arow, ks * 4 + agrp);
#pragma unroll
      for (int nj = 0; nj < 2; nj++) bfr[nj] = lds8(lB, w * 32 + nj * 16 + arow, ks * 4 + agrp);
#pragma unroll
      for (int mi = 0; mi < 4; mi++)
#pragma unroll
        for (int nj = 0; nj < 2; nj++)
          acc[mi][nj] = __builtin_amdgcn_mfma_f32_16x16x32_bf16(af[mi], bfr[nj], acc[mi][nj], 0, 0, 0);
    }
  }
#pragma unroll
  for (int mi = 0; mi < 4; mi++)
#pragma unroll
    for (int reg = 0; reg < 4; reg++) {
      int i = m0 + mi * 16 + agrp * 4 + reg;
#pragma unroll
      for (int nj = 0; nj < 2; nj++) {
        int col = n0 + w * 32 + nj * 16 + arow;
        dout[(size_t)i * E_ + col] = acc[mi][nj][reg];
      }
    }
}

// ---------------- flash attention ----------------
// v10: R8's exact proven k_attn (60.6us, VGPR 112, zero spill). R9's intra-wave
// pipeline (double sacc state) spilled to scratch (WRITE 20.5->34.7MB) -> 76.6us.
// No VGPR headroom for 2-deep per-wave state; cross-wave TLP is the overlap mechanism.
__device__ const int4 kChunk[38] = {
  { 8,0, 8, 8},{ 8,9,17, 9},{12,0, 8,19},{12,9,17,20},
  { 7,0, 7, 6},{ 7,8,15, 7},{10,0, 7,13},{11,0, 7,16},{11,8,15,17},{11,16,23,18},
  {12,18,25,21},{14,0, 7,26},{14,8,15,27},{15,0, 7,30},{15,8,15,31},{15,16,23,32},
  {15,24,31,33},{ 3,0, 7,-1},
  { 6,0, 6, 4},{ 6,7,13, 5},{ 9,0, 6,10},{ 9,7,13,11},{10,8,14,14},{10,15,21,15},
  {13,0, 6,22},{13,7,13,23},{13,14,20,24},{13,21,27,25},{14,16,22,28},{14,23,29,29},
  { 5,0, 5, 2},{ 5,6,11, 3},{ 9,14,19,12},{ 2,0, 5,-1},
  { 4,0, 4, 0},{ 4,5, 9, 1},{ 1,0, 3,-1},{ 0,0, 1,-1}
};

__device__ __forceinline__ short8 mkfrag(u16x4 pv) {
  union { u16x4 v; unsigned u[2]; } pun; pun.v = pv;
  union { short8 s; unsigned u[4]; } z;
  z.u[0] = pun.u[0]; z.u[1] = pun.u[1]; z.u[2] = 0; z.u[3] = 0;
  return z.s;
}

__device__ __forceinline__ void qk_phase2(const char* lKc, const short8 qf[2][2],
    const int kOff[2][4], f32x4 zero4, f32x4 sacc[2][4]) {
#pragma unroll
  for (int ct = 0; ct < 4; ct++) {
    short8 kf = *(const short8*)(lKc + kOff[0][ct]);
    sacc[0][ct] = __builtin_amdgcn_mfma_f32_16x16x32_bf16(qf[0][0], kf, zero4, 0, 0, 0);
    sacc[1][ct] = __builtin_amdgcn_mfma_f32_16x16x32_bf16(qf[1][0], kf, zero4, 0, 0, 0);
  }
#pragma unroll
  for (int ct = 0; ct < 4; ct++) {
    short8 kf = *(const short8*)(lKc + kOff[1][ct]);
    sacc[0][ct] = __builtin_amdgcn_mfma_f32_16x16x32_bf16(qf[0][1], kf, sacc[0][ct], 0, 0, 0);
    sacc[1][ct] = __builtin_amdgcn_mfma_f32_16x16x32_bf16(qf[1][1], kf, sacc[1][ct], 0, 0, 0);
  }
}

__device__ __forceinline__ void softmax_half(const f32x4 sacc[4], const short8 piF,
    const short8 pjF[4], char* lPh, int kv0, int ig_base, int arow, int agrp,
    const int wOff[4][4], float mrow[4], f32x4 oacc[4], f32x4& o4) {
  f32x4 eps4 = {1e-8f, 1e-8f, 1e-8f, 1e-8f};
  f32x4 nwa[4];
#pragma unroll
  for (int ct = 0; ct < 4; ct++)
    nwa[ct] = __builtin_amdgcn_mfma_f32_16x16x32_bf16(piF, pjF[ct], eps4, 0, 0, 0);
  float sv[4][4];
  float rmax[4];
  if (kv0 + 63 > ig_base) {   // tile touches/crosses the diagonal: apply causal mask
#pragma unroll
    for (int ct = 0; ct < 4; ct++) {
      int jg = kv0 + ct * 16 + arow;
#pragma unroll
      for (int reg = 0; reg < 4; reg++) {
        int ig = ig_base + agrp * 4 + reg;
        float xv = sacc[ct][reg];
        if (jg > ig) xv = -1e30f;
        sv[ct][reg] = xv;
      }
    }
  } else {
#pragma unroll
    for (int ct = 0; ct < 4; ct++)
#pragma unroll
      for (int reg = 0; reg < 4; reg++)
        sv[ct][reg] = sacc[ct][reg];
  }
#pragma unroll
  for (int reg = 0; reg < 4; reg++)
    rmax[reg] = redmax16(fmaxf(fmaxf(sv[0][reg], sv[1][reg]), fmaxf(sv[2][reg], sv[3][reg])));
  // defer-max (T13): rescale only when a row's max grew by more than THR (log2 domain).
  bool ok = (rmax[0] <= mrow[0] + 11.5f) & (rmax[1] <= mrow[1] + 11.5f) &
            (rmax[2] <= mrow[2] + 11.5f) & (rmax[3] <= mrow[3] + 11.5f);
  if (!__all(ok)) {
    float alpha[4];
#pragma unroll
    for (int reg = 0; reg < 4; reg++) {
      float mn = fmaxf(mrow[reg], rmax[reg]);
      alpha[reg] = __builtin_amdgcn_exp2f(mrow[reg] - mn);
      mrow[reg] = mn;
    }
#pragma unroll
    for (int dt = 0; dt < 4; dt++) {
      f32x4 o = oacc[dt];
      o.x *= alpha[0]; o.y *= alpha[1]; o.z *= alpha[2]; o.w *= alpha[3];
      oacc[dt] = o;
    }
    o4.x *= alpha[0]; o4.y *= alpha[1]; o4.z *= alpha[2]; o4.w *= alpha[3];
  }
#pragma unroll
  for (int ct = 0; ct < 4; ct++)
#pragma unroll
    for (int reg = 0; reg < 4; reg++)
      sv[ct][reg] = __builtin_amdgcn_exp2f(sv[ct][reg] - mrow[reg]) * nwa[ct][reg];
  // P -> bf16 via packed convert (RNE, same as f2bf)
#pragma unroll
  for (int ct = 0; ct < 4; ct++) {
#pragma unroll
    for (int rp = 0; rp < 2; rp++) {
      unsigned pk;
      asm("v_cvt_pk_bf16_f32 %0, %1, %2" : "=v"(pk) : "v"(sv[ct][rp * 2]), "v"(sv[ct][rp * 2 + 1]));
      *(unsigned short*)(lPh + wOff[ct][rp * 2 + 0]) = (unsigned short)pk;
      *(unsigned short*)(lPh + wOff[ct][rp * 2 + 1]) = (unsigned short)(pk >> 16);
    }
  }
}

__device__ __forceinline__ void pv2(const char* lPw, const char* lVc,
    const int pOff[2], const int kOff[2][4], f32x4 oacc0[4], f32x4 oacc1[4],
    f32x4& o40, f32x4& o41) {
  // ones-column trick: B = all-ones -> every output column = row-sum of P = l.
  const short8 ones = {16256, 16256, 16256, 16256, 16256, 16256, 16256, 16256};  // bf16 1.0
#pragma unroll
  for (int ks = 0; ks < 2; ks++) {
    short8 pf0 = *(const short8*)(lPw + pOff[ks]);
    short8 pf1 = *(const short8*)(lPw + 2048 + pOff[ks]);
    o40 = __builtin_amdgcn_mfma_f32_16x16x32_bf16(pf0, ones, o40, 0, 0, 0);
    o41 = __builtin_amdgcn_mfma_f32_16x16x32_bf16(pf1, ones, o41, 0, 0, 0);
#pragma unroll
    for (int dt = 0; dt < 4; dt++) {
      short8 vf = *(const short8*)(lVc + kOff[ks][dt]);
      oacc0[dt] = __builtin_amdgcn_mfma_f32_16x16x32_bf16(pf0, vf, oacc0[dt], 0, 0, 0);
      oacc1[dt] = __builtin_amdgcn_mfma_f32_16x16x32_bf16(pf1, vf, oacc1[dt], 0, 0, 0);
    }
  }
}

__global__ __launch_bounds__(256, 2) void k_attn(const unsigned short* __restrict__ qr,
    const unsigned short* __restrict__ kr, const unsigned short* __restrict__ vb,
    const unsigned short* __restrict__ pb, unsigned short* __restrict__ ob,
    unsigned short* __restrict__ ObP, float* __restrict__ ml) {
  __shared__ unsigned short lK[2][64 * 64];
  __shared__ unsigned short lV[2][64 * 64];     // V^T tile, staged like K
  __shared__ unsigned short lP[4][2][16 * 64];  // per-wave, per-half P staging
  int id = blockIdx.x;
  int xcd = id & 7, slt = id >> 3;
  int bh = xcd * 4 + (slt & 3);
  int4 ck = kChunk[slt >> 2];
  int qt2 = ck.x, j0 = ck.y, j1 = ck.z, part = ck.w;
  int t = threadIdx.x, w = t >> 6, lane = t & 63;
  int arow = lane & 15, agrp = lane >> 4;
  int q0 = qt2 * 128;
  size_t base = (size_t)bh * S_ * 64;   // also the V^T base: bh*64*S
  size_t bhS = (size_t)bh * S_;

  // ---- hoisted LDS offsets (loop-invariant) ----
  int kOff[2][4], pOff[2], wOff[4][4];
#pragma unroll
  for (int ks = 0; ks < 2; ks++) {
    pOff[ks] = arow * 128 + (((ks * 4 + agrp) ^ (arow & 7)) << 4);
#pragma unroll
    for (int ct = 0; ct < 4; ct++) {
      int row = ct * 16 + arow;
      kOff[ks][ct] = row * 128 + (((ks * 4 + agrp) ^ (row & 7)) << 4);
    }
  }
#pragma unroll
  for (int ct = 0; ct < 4; ct++) {
    int col2 = (ct * 16 + arow) * 2;
#pragma unroll
    for (int rr = 0; rr < 4; rr++) {
      int r = agrp * 4 + rr;
      wOff[ct][rr] = r * 128 + (col2 ^ ((r & 7) << 4));
    }
  }

  // ---- hoisted per-lane global pointers (element units) ----
  const unsigned short* kSrc[2];
  const unsigned short* vSrc[2];
  unsigned short* kDst[2];
  unsigned short* vDst[2];
#pragma unroll
  for (int j = 0; j < 2; j++) {
    int c = j * 256 + w * 64 + lane;
    int row = c >> 3, slot = c & 7;
    kSrc[j] = kr + base + (size_t)row * 64 + ((slot ^ (row & 7)) << 3);
    vSrc[j] = vb + base + (size_t)row * S_ + ((slot ^ (row & 7)) << 3);
    kDst[j] = &lK[0][(j * 256 + w * 64) * 8];
    vDst[j] = &lV[0][(j * 256 + w * 64) * 8];
  }
  const unsigned short* pjSrc[4];
#pragma unroll
  for (int ct = 0; ct < 4; ct++) pjSrc[ct] = pb + (bhS + ct * 16 + arow) * 4;

  short8 qf[2][2];
  short8 piF[2];
  float mrow[2][4];
  f32x4 oacc[2][4];
  f32x4 o4[2];
  f32x4 zero4 = {0.f, 0.f, 0.f, 0.f};
#pragma unroll
  for (int hh = 0; hh < 2; hh++) {
#pragma unroll
    for (int ks = 0; ks < 2; ks++)
      qf[hh][ks] = *(const short8*)&qr[base + (size_t)(q0 + hh * 64 + w * 16 + arow) * 64 + ks * 32 + agrp * 8];
    u16x4 pv = {0, 0, 0, 0};
    if (agrp == 0) pv = *(const u16x4*)&pb[(bhS + q0 + hh * 64 + w * 16 + arow) * 4];
    piF[hh] = mkfrag(pv);
#pragma unroll
    for (int reg = 0; reg < 4; reg++) mrow[hh][reg] = -1e30f;
#pragma unroll
    for (int dt = 0; dt < 4; dt++) oacc[hh][dt] = zero4;
    o4[hh] = zero4;
  }

  auto stageK = [&](int jt, int buf) {
#pragma unroll
    for (int j = 0; j < 2; j++)
      gload_lds16(kSrc[j] + jt * 4096, kDst[j] + buf * 4096);
  };
  auto stageV = [&](int jt, int buf) {
#pragma unroll
    for (int j = 0; j < 2; j++)
      gload_lds16(vSrc[j] + jt * 64, vDst[j] + buf * 4096);
  };
  auto loadPj = [&](int jt, u16x4 pj[4]) {
#pragma unroll
    for (int ct = 0; ct < 4; ct++) {
      u16x4 z = {0, 0, 0, 0};
      if (agrp == 0) z = *(const u16x4*)(pjSrc[ct] + jt * 256);
      pj[ct] = z;
    }
  };

  // prologue: stage tile j0 into buffer 0
  u16x4 pjv[4], pjvn[4];
  stageK(j0, 0);
  stageV(j0, 0);
  loadPj(j0, pjv);
  __syncthreads();

  char* lPw = (char*)&lP[w][0][0];
  int nt = j1 - j0 + 1;
  for (int i = 0; i < nt; i++) {
    int cur = i & 1;
    int kv0 = (j0 + i) * 64;
    bool hn = (i + 1) < nt;
    if (hn) {                       // async prefetch next K/V tile into other buffer
      stageK(j0 + i + 1, cur ^ 1);
      stageV(j0 + i + 1, cur ^ 1);
    }

    f32x4 sacc[2][4];
    __builtin_amdgcn_s_setprio(1);
    qk_phase2((const char*)lK + cur * 8192, qf, kOff, zero4, sacc);
    __builtin_amdgcn_s_setprio(0);

    short8 pjF[4];
#pragma unroll
    for (int ct = 0; ct < 4; ct++) pjF[ct] = mkfrag(pjv[ct]);
#pragma unroll
    for (int hh = 0; hh < 2; hh++)
      softmax_half(sacc[hh], piF[hh], pjF, lPw + hh * 2048, kv0, q0 + hh * 64 + w * 16,
                   arow, agrp, wOff, mrow[hh], oacc[hh], o4[hh]);

    if (hn) loadPj(j0 + i + 1, pjvn);

    // lP is wave-private: order the wave's own ds_write -> ds_read with a counted
    // wait + scheduler fence (rule #18).
    asm volatile("s_waitcnt lgkmcnt(0)" ::: "memory");
    __builtin_amdgcn_sched_barrier(0);
    __builtin_amdgcn_s_setprio(1);
    pv2(lPw, (const char*)lV + cur * 8192, pOff, kOff, oacc[0], oacc[1], o4[0], o4[1]);
    __builtin_amdgcn_s_setprio(0);
    if (hn) {
#pragma unroll
      for (int ct = 0; ct < 4; ct++) pjv[ct] = pjvn[ct];
    }
    __syncthreads();  // all waves done reading buf[cur]; next-tile stage complete
  }

  if (part >= 0) {
    unsigned short* Op = ObP + ((size_t)bh * 34 + part) * 8192;
    float* mlp = ml + ((size_t)bh * 34 + part) * 256;
#pragma unroll
    for (int hh = 0; hh < 2; hh++) {
#pragma unroll
      for (int dt = 0; dt < 4; dt++)
#pragma unroll
        for (int reg = 0; reg < 4; reg++) {
          int row = hh * 64 + w * 16 + agrp * 4 + reg;
          Op[row * 64 + dt * 16 + arow] = f2bf(oacc[hh][dt][reg]);
        }
      if (arow == 0) {
#pragma unroll
        for (int reg = 0; reg < 4; reg++) {
          int row = hh * 64 + w * 16 + agrp * 4 + reg;
          mlp[row] = mrow[hh][reg];
          mlp[128 + row] = o4[hh][reg];   // l from the ones-column accumulator
        }
      }
    }
  } else {
    int b = bh >> 4, h8 = bh & 15;
#pragma unroll
    for (int hh = 0; hh < 2; hh++) {
      f32x4 inv4;
      inv4.x = 1.f / o4[hh].x; inv4.y = 1.f / o4[hh].y;
      inv4.z = 1.f / o4[hh].z; inv4.w = 1.f / o4[hh].w;
#pragma unroll
      for (int dt = 0; dt < 4; dt++)
#pragma unroll
        for (int reg = 0; reg < 4; reg++) {
          int i = q0 + hh * 64 + w * 16 + agrp * 4 + reg;
          int d = dt * 16 + arow;
          float v = oacc[hh][dt][reg] * inv4[reg];
          ob[((size_t)(b * S_ + i) * H_ + h8) * 64 + d] = f2bf(v);
        }
    }
  }
}

__global__ __launch_bounds__(256) void k_merge(const unsigned short* __restrict__ ObP,
    const float* __restrict__ ml, unsigned short* __restrict__ ob) {
  int qx = blockIdx.x, bh = blockIdx.y;
  int qt2 = 4 + qx;
  int np = qt2 <= 8 ? 2 : (qt2 <= 12 ? 3 : 4);
  int bslot = qt2 <= 8 ? (qt2 - 4) * 2 : (qt2 <= 12 ? 10 + (qt2 - 9) * 3 : 22 + (qt2 - 13) * 4);
  int t = threadIdx.x;
  int r = t >> 1, dh = (t & 1) * 32;
  float mp[4], lp[4];
  float m = -1e30f;
  for (int p2 = 0; p2 < np; p2++) {
    const float* mlp = ml + ((size_t)bh * 34 + bslot + p2) * 256;
    mp[p2] = mlp[r]; lp[p2] = mlp[128 + r];
    m = fmaxf(m, mp[p2]);
  }
  float a[4], l = 0.f;
  for (int p2 = 0; p2 < np; p2++) { a[p2] = __builtin_amdgcn_exp2f(mp[p2] - m); l = fmaf(lp[p2], a[p2], l); }
  float inv = 1.f / l;
  for (int p2 = 0; p2 < np; p2++) a[p2] *= inv;
  int i = qt2 * 128 + r, b = bh >> 4, h = bh & 15;
  unsigned short* op = ob + ((size_t)(b * S_ + i) * H_ + h) * 64 + dh;
#pragma unroll
  for (int q = 0; q < 8; q++) {
    float a0 = 0.f, a1 = 0.f, a2 = 0.f, a3 = 0.f;
    for (int p2 = 0; p2 < np; p2++) {
      const unsigned short* Op = ObP + ((size_t)bh * 34 + bslot + p2) * 8192 + r * 64 + dh + q * 4;
      u16x4 xx = *(const u16x4*)Op;
      a0 = fmaf(bf2f(xx.x), a[p2], a0);
      a1 = fmaf(bf2f(xx.y), a[p2], a1);
      a2 = fmaf(bf2f(xx.z), a[p2], a2);
      a3 = fmaf(bf2f(xx.w), a[p2], a3);
    }
    u16x4 o; o.x = f2bf(a0); o.y = f2bf(a1); o.z = f2bf(a2); o.w = f2bf(a3);
    *(u16x4*)(op + q * 4) = o;
  }
}

extern "C" void kernel_launch(void* const* d_in, const int* in_sizes, int n_in,
                              void* d_out, int out_size, void* d_ws, size_t ws_size,
                              hipStream_t stream) {
  const float* x  = (const float*)d_in[0];
  const float* Wq = (const float*)d_in[1];
  const float* Wk = (const float*)d_in[2];
  const float* Wv = (const float*)d_in[3];
  const float* Wr = (const float*)d_in[4];
  const float* Wo = (const float*)d_in[5];
  float* dout = (float*)d_out;

  char* p = (char*)d_ws;
  auto alloc = [&](size_t bytes) -> char* {
    char* r = p; p += (bytes + 255) & ~(size_t)255; return r;
  };
  unsigned short* xb   = (unsigned short*)alloc((size_t)BS_ * E_ * 2);     // dead after qkv
  unsigned short* wt   = (unsigned short*)alloc((size_t)4 * E_ * E_ * 2);
  float* cosc          = (float*)alloc((size_t)CT_ * 32 * 4);
  float* sinc          = (float*)alloc((size_t)CT_ * 32 * 4);
  float* probs         = (float*)alloc((size_t)BH_ * S_ * 4 * 4);
  unsigned short* pb   = (unsigned short*)alloc((size_t)BH_ * S_ * 4 * 2); // bf16 probs
  // the next 4 buffers (18 MB contiguous) are dead by k_attn time -> reused for partials
  float* logits        = (float*)alloc((size_t)BS_ * 64 * 4);
  float* epos          = (float*)alloc((size_t)BH_ * S_ * 4 * 4);
  float* cw            = (float*)alloc((size_t)BH_ * S_ * 32 * 4);
  float* sw            = (float*)alloc((size_t)BH_ * S_ * 32 * 4);
  unsigned short* qrb  = (unsigned short*)alloc((size_t)BH_ * S_ * 64 * 2);
  unsigned short* krb  = (unsigned short*)alloc((size_t)BH_ * S_ * 64 * 2);
  unsigned short* vbb  = (unsigned short*)alloc((size_t)BH_ * S_ * 64 * 2); // V^T [bh][d][s]
  unsigned short* obb  = (unsigned short*)alloc((size_t)BS_ * E_ * 2);
  float* chunkSum      = (float*)alloc((size_t)BH_ * 8 * 4 * 4);
  float* chunkBase     = (float*)alloc((size_t)BH_ * 8 * 4 * 4);
  if ((size_t)(p - (char*)d_ws) > ws_size) return;  // workspace too small -> visible failure

  // partials: bf16 O (34 slots) in the 18 MB dead span; f32 m/l aliased onto dead xb
  unsigned short* ObP = (unsigned short*)logits;      // 32*34*8192 u16 = 17.8 MB
  float* mlbuf = (float*)xb;                          // 32*34*256 f32 = 1.1 MB (xb dead)

  k_prep<<<4096 + 1024 + 260 + 256, 256, 0, stream>>>(x, Wq, Wk, Wv, Wo, Wr,
                                                      xb, wt, cosc, sinc, logits);
  k_scan1<<<BH_ * 8, 256, 0, stream>>>(logits, probs, pb, epos, chunkSum);
  k_scan2<<<1, 64, 0, stream>>>(chunkSum, chunkBase);
  k_cwsw<<<dim3(S_ / 8, BH_), 256, 0, stream>>>(probs, epos, chunkBase, cosc, sinc, cw, sw);
  k_gemm_qkv<<<dim3(8, 32, 3), 256, 0, stream>>>(xb, wt, cw, sw, qrb, krb, vbb);
  k_attn<<<dim3(38 * BH_), 256, 0, stream>>>(qrb, krb, vbb, pb, obb, ObP, mlbuf);
  k_merge<<<dim3(12, BH_), 256, 0, stream>>>(ObP, mlbuf, obb);
  k_gemm_out<<<dim3(8, 64), 256, 0, stream>>>(obb, wt + (size_t)3 * E_ * E_, dout);
}